// Round 6
// baseline (451.557 us; speedup 1.0000x reference)
//
#include <hip/hip_runtime.h>
#include <math.h>

// Problem constants
#define BB 256          // batch
#define CC 256          // channels
#define MN 196          // H*W
#define TRI 32896       // C*(C+1)/2

// Split-f16 storage: u32 = {lo16: f16(hi), hi16: f16(32v - hi)} at x32 scale.
#define MSC 32.0f
#define INV_MSC  (1.0f/32.0f)
#define INV_MSC2 (1.0f/1024.0f)

typedef _Float16 f16;
typedef f16   f16x8 __attribute__((ext_vector_type(8)));
typedef float f32x4 __attribute__((ext_vector_type(4)));
typedef unsigned u32x4 __attribute__((ext_vector_type(4)));

__device__ __forceinline__ unsigned pack_split(float v) {
    f16 h = (f16)v;
    f16 l = (f16)(v - (float)h);
    return (unsigned)__builtin_bit_cast(unsigned short, h) |
           ((unsigned)__builtin_bit_cast(unsigned short, l) << 16);
}
__device__ __forceinline__ float unpack_split(unsigned w) {
    f16 h = __builtin_bit_cast(f16, (unsigned short)(w & 0xffffu));
    f16 l = __builtin_bit_cast(f16, (unsigned short)(w >> 16));
    return (float)h + (float)l;
}
__device__ __forceinline__ f16x8 swap_pairs(f16x8 v) {
    return __builtin_shufflevector(v, v, 1, 0, 3, 2, 5, 4, 7, 6);
}
__device__ __forceinline__ void gload_lds16(const unsigned* g, const void* l) {
    __builtin_amdgcn_global_load_lds(
        (__attribute__((address_space(1))) void*)(size_t)g,
        (__attribute__((address_space(3))) void*)(unsigned)(size_t)l,
        16, 0, 0);
}

// ---------------------------------------------------------------------------
// Fused xsplit: per (b,c) row compute mean+var in-wave, write split-f16
// centered row padded K 196 -> 256 with zeros (so cov is a plain 256-K GEMM).
// xs[batch] is exactly 256x256 u32 = one slot.
// ---------------------------------------------------------------------------
__global__ __launch_bounds__(256) void xsplit_kernel(const float* __restrict__ x,
                                                     float* __restrict__ vr,
                                                     unsigned* __restrict__ xs, int b0) {
    int wave = (blockIdx.x * 256 + threadIdx.x) >> 6;   // bl*256 + c
    int lane = threadIdx.x & 63;
    int bl = wave >> 8;
    int c  = wave & 255;
    int bg = b0 + bl;
    const float* row = x + ((size_t)bg * CC + c) * MN;
    float a0 = row[lane], a1 = row[lane + 64], a2 = row[lane + 128];
    float a3 = (lane < MN - 192) ? row[lane + 192] : 0.0f;
    float s = a0 + a1 + a2 + a3;
    float q = a0 * a0 + a1 * a1 + a2 * a2 + a3 * a3;
    #pragma unroll
    for (int off = 32; off > 0; off >>= 1) {
        s += __shfl_xor(s, off, 64);
        q += __shfl_xor(q, off, 64);
    }
    float m = s * (1.0f / MN);
    if (lane == 0) vr[bg * CC + c] = q * (1.0f / MN) - m * m;
    unsigned* orow = xs + ((size_t)bl * CC + c) * 256;
    orow[lane]       = pack_split(MSC * (a0 - m));
    orow[lane + 64]  = pack_split(MSC * (a1 - m));
    orow[lane + 128] = pack_split(MSC * (a2 - m));
    orow[lane + 192] = (lane < 4) ? pack_split(MSC * (a3 - m)) : 0u;
}

// normA[b] = sum_c vr[b,c] (per chunk)
__global__ __launch_bounds__(256) void norm_kernel(const float* __restrict__ vr,
                                                   float* __restrict__ inv,
                                                   float* __restrict__ snorm,
                                                   float* __restrict__ invs, int b0) {
    __shared__ float red[256];
    int b = b0 + blockIdx.x, i = threadIdx.x;
    red[i] = vr[b * CC + i];
    __syncthreads();
    for (int s = 128; s > 0; s >>= 1) {
        if (i < s) red[i] += red[i + s];
        __syncthreads();
    }
    if (i == 0) {
        float n = red[0];
        inv[b] = 1.0f / n;
        float sq = sqrtf(n);
        snorm[b] = sq;
        invs[b] = 1.0f / sq;
    }
}

// ---------------------------------------------------------------------------
// Split-f16 MFMA GEMM, occupancy-optimized.
// 128x128 tile, 256 threads = 4 waves (2x2), wave tile 64x64 (4x4 16x16
// frags), mfma_f32_16x16x32_f16 x2 passes (bv / swap(bv)) per K-chunk.
// K-chunk = 16 u32 (one MFMA-K per chunk): staging LDS = 2 bufs x (A 8KB +
// B 8KB) = 32 KiB total -> 4 blocks/CU resident (16 waves/CU). Four
// UNSYNCHRONIZED blocks per CU interleave so each block's per-chunk barrier
// drain is hidden by the other three (TLP latency hiding).
// LDS swizzle: stored granule position p holds logical granule p ^ ((row>>1)&3)
// (involution, both sides: pre-swizzled global source + swizzled read) ->
// b128 frag reads spread across all 8 bank-quads (2-way = free).
// Epilogue: E/C bounced through LDS in two 64-row passes (1KB/inst coalesced),
// reusing the 32 KiB staging space.
// FINAL: triu(acc)*INV_MSC2 -> f32 out; (1,0) tile blocks exit early.
// XCD-chunked blockIdx swizzle (grid divisible by 8) for L2 panel reuse.
// ---------------------------------------------------------------------------
template <bool FINAL>
__global__ __launch_bounds__(256) void gemm256(const unsigned* __restrict__ Ag,
                                               const unsigned* __restrict__ Bg,
                                               const unsigned* __restrict__ Eg,
                                               void* __restrict__ Cg,
                                               const float alpha0, const float beta0,
                                               const float diag_add,
                                               const float* __restrict__ Sg, int b0) {
    __shared__ __align__(16) unsigned char smem[32768];
    // staging: A [2][128 rows][64B] at 0..16384 ; B at 16384..32768
    // epilogue union: tile[64][128] u32 (full 32KB)

    int bid = blockIdx.x;
    const int nwg = gridDim.x;
    if ((nwg & 7) == 0) {                   // bijective XCD-chunked swizzle
        const int cpx = nwg >> 3;
        bid = (bid & 7) * cpx + (bid >> 3);
    }
    const int bl = bid >> 2;
    const int t  = bid & 3;
    const int ti = t >> 1, tj = t & 1;
    if (FINAL && ti == 1 && tj == 0) return;   // strictly-lower tile unused
    const int bg = b0 + bl;
    const int tid  = threadIdx.x;
    const int lane = tid & 63;
    const int wid  = tid >> 6;              // 0..3
    const int wr = wid >> 1, wc = wid & 1;
    const int h = lane >> 4;                // 0..3 (k-group of MFMA A/B frag)
    const int d = lane & 15;                // frag row-within-16 / C col

    const unsigned* Abase = Ag + (size_t)bl * (CC * CC) + (size_t)(ti * 128) * 256;
    const unsigned* Bbase = Bg + (size_t)bl * (CC * CC) + (size_t)(tj * 128) * 256;

    // staging roles: waves 0-1 -> A rows (wid&1)*64..+63, waves 2-3 -> B.
    // lane -> (row = rbase+i*16+(lane>>2), dest granule p = lane&3);
    // source logical granule = p ^ ((row>>1)&3) = p ^ ((lane>>3)&3).
    const unsigned* gpan = (wid < 2) ? Abase : Bbase;
    const int lbank = (wid < 2) ? 0 : 16384;
    const int rbase = (wid & 1) * 64;
    const int sr = lane >> 2;                           // 0..15
    const int sg = (lane & 3) ^ ((lane >> 3) & 3);      // pre-swizzled src granule
    const unsigned* gsl = gpan + (size_t)(rbase + sr) * 256 + (sg << 2);

    auto STAGE = [&](int nb, int ks) {
        #pragma unroll
        for (int i = 0; i < 4; ++i)
            gload_lds16(gsl + (size_t)(i * 16) * 256 + ks * 16,
                        smem + lbank + nb * 8192 + (rbase + i * 16) * 64);
    };

    // frag read byte offsets; swizzle term is lane-constant: (h ^ ((d>>1)&3))<<4
    const int swz = ((h ^ ((d >> 1) & 3)) << 4);
    int aoff[4], boff[4];
    #pragma unroll
    for (int ib = 0; ib < 4; ++ib) {
        aoff[ib] = (wr * 64 + ib * 16 + d) * 64 + swz;
        boff[ib] = 16384 + (wc * 64 + ib * 16 + d) * 64 + swz;
    }

    f32x4 acc[4][4];
    #pragma unroll
    for (int i = 0; i < 4; ++i)
        #pragma unroll
        for (int j = 0; j < 4; ++j) acc[i][j] = 0.0f;

    STAGE(0, 0);
    __syncthreads();
    #pragma unroll 1
    for (int ks = 0; ks < 16; ++ks) {
        const int nb = ks & 1;
        if (ks < 15) STAGE(nb ^ 1, ks + 1);
        const char* base = (const char*)smem + nb * 8192;
        f16x8 av[4], bv[4], bw[4];
        #pragma unroll
        for (int ib = 0; ib < 4; ++ib)
            av[ib] = *(const f16x8*)(base + aoff[ib]);
        #pragma unroll
        for (int jb = 0; jb < 4; ++jb) {
            bv[jb] = *(const f16x8*)(base + boff[jb]);
            bw[jb] = swap_pairs(bv[jb]);
        }
        #pragma unroll
        for (int ib = 0; ib < 4; ++ib)
            #pragma unroll
            for (int jb = 0; jb < 4; ++jb) {
                acc[ib][jb] = __builtin_amdgcn_mfma_f32_16x16x32_f16(av[ib], bv[jb], acc[ib][jb], 0, 0, 0);
                acc[ib][jb] = __builtin_amdgcn_mfma_f32_16x16x32_f16(av[ib], bw[jb], acc[ib][jb], 0, 0, 0);
            }
        __syncthreads();   // staged chunk landed (vmcnt drained) + reads done
    }

    // C/D frag: col = lane&15 (=d), row = h*4 + q  (harness-verified)
    const int li0 = wr * 64 + h * 4;        // local row base (+ib*16+q)
    const int lj0 = wc * 64 + d;            // local col (+jb*16)
    const int gi0 = ti * 128 + li0;
    const int gj0 = tj * 128 + lj0;
    unsigned* tile = (unsigned*)smem;       // 64x128 u32 epilogue buffer

    if (!FINAL) {
        const float sc = (Sg != nullptr) ? Sg[bg] : 1.0f;
        const float al = alpha0 * sc;
        const float be = beta0 * sc;
        unsigned* Cb = (unsigned*)Cg + (size_t)bl * CC * CC;
        const unsigned* Eb = (Eg != nullptr) ? Eg + (size_t)bl * CC * CC : nullptr;

        #pragma unroll
        for (int p = 0; p < 2; ++p) {       // two 64-row passes
            __syncthreads();                // staging reads / prev store done
            if (Eb) {                       // coalesced 1KB/inst E half-tile
                #pragma unroll
                for (int it = 0; it < 8; ++it) {
                    int f = it * 256 + tid;
                    int r = f >> 5, c4 = f & 31;
                    *(u32x4*)&tile[r * 128 + c4 * 4] =
                        *(const u32x4*)&Eb[(size_t)(ti * 128 + p * 64 + r) * CC + tj * 128 + c4 * 4];
                }
            }
            __syncthreads();
            if (wr == p) {                  // owner waves: read-modify-write own cells
                #pragma unroll
                for (int ib = 0; ib < 4; ++ib)
                    #pragma unroll
                    for (int jb = 0; jb < 4; ++jb)
                        #pragma unroll
                        for (int q = 0; q < 4; ++q) {
                            int lr2 = h * 4 + ib * 16 + q;      // 0..63 in pass
                            int lc  = lj0 + jb * 16;
                            float val = al * acc[ib][jb][q];
                            if (Eb) val += be * unpack_split(tile[lr2 * 128 + lc]);
                            if (gi0 + ib * 16 + q == gj0 + jb * 16) val += diag_add;
                            tile[lr2 * 128 + lc] = pack_split(val);
                        }
            }
            __syncthreads();
            #pragma unroll
            for (int it = 0; it < 8; ++it) {   // coalesced 1KB/inst C half-tile
                int f = it * 256 + tid;
                int r = f >> 5, c4 = f & 31;
                *(u32x4*)&Cb[(size_t)(ti * 128 + p * 64 + r) * CC + tj * 128 + c4 * 4] =
                    *(const u32x4*)&tile[r * 128 + c4 * 4];
            }
        }
    } else {
        float* ob = (float*)Cg + (size_t)bg * TRI;
        #pragma unroll
        for (int ib = 0; ib < 4; ++ib)
            #pragma unroll
            for (int jb = 0; jb < 4; ++jb) {
                int gib = gi0 + ib * 16;
                int gj  = gj0 + jb * 16;
                #pragma unroll
                for (int q = 0; q < 4; ++q) {
                    int gi = gib + q;
                    if (gj >= gi)
                        ob[gi * CC - (gi * (gi - 1)) / 2 - gi + gj] = acc[ib][jb][q] * INV_MSC2;
                }
            }
    }
}

// ---------------------------------------------------------------------------
// Per chunk of g batches (4 slots of 256KB/batch):
//   xs  = split(MSC*(x-mu)), K padded to 256   -> s1
//   A   = Gram(xs)*inv/(MSC*MN)                -> s0   (plain gemm, Sg=inv)
//   Y1  = -0.5 A@A + 1.5 A                     -> s1
//   ZY1 = 0.25 A@Y1 - 0.75 Y1 + 1.5 I          -> s2
//   Y2' = sqrt(n)*(Y1@ZY1)                     -> s3
//   Z2' = (1/sqrt(n))*(-0.5 ZY1@A + 1.5 ZY1)   -> s1
//   T   = -0.5 Z2'@Y2' + 1.5 I                 -> s0
//   out = triu(Y2'@T)/MSC^2                    -> d_out
// Scalar scratch in the tail of d_out (only the last FINAL writes there).
// ---------------------------------------------------------------------------
extern "C" void kernel_launch(void* const* d_in, const int* in_sizes, int n_in,
                              void* d_out, int out_size, void* d_ws, size_t ws_size,
                              hipStream_t stream) {
    const float* x = (const float*)d_in[0];
    float* out = (float*)d_out;
    unsigned* ws = (unsigned*)d_ws;

    const int SCR = BB * CC + 3 * BB;           // vr, inv, snorm, invs
    float* vr    = out + (out_size - SCR);
    float* inv   = vr + BB * CC;
    float* snorm = inv + BB;
    float* invs  = snorm + BB;

    size_t per_b = 4ull * CC * CC * sizeof(unsigned);   // 1 MiB per batch
    int gmax = (int)(ws_size / per_b);
    int g = 1;
    while (g * 2 <= gmax && g * 2 <= BB) g *= 2;

    size_t slotf = (size_t)g * CC * CC;
    unsigned* s0 = ws;
    unsigned* s1 = ws + slotf;
    unsigned* s2 = ws + 2 * slotf;
    unsigned* s3 = ws + 3 * slotf;

    for (int b0 = 0; b0 < BB; b0 += g) {
        xsplit_kernel<<<g * 64, 256, 0, stream>>>(x, vr, s1, b0);
        norm_kernel<<<g, 256, 0, stream>>>(vr, inv, snorm, invs, b0);
        // A = Gram(xs) * inv / (MSC*MN)   (stored MSC-scaled)
        gemm256<false><<<g * 4, 256, 0, stream>>>(s1, s1, nullptr, (void*)s0,
                                                  1.0f / (MSC * MN), 0.0f, 0.0f, inv, b0);
        // Y1 = -0.5*(A@A) + 1.5*A
        gemm256<false><<<g * 4, 256, 0, stream>>>(s0, s0, s0, (void*)s1, -0.5f * INV_MSC, 1.5f, 0.0f, nullptr, b0);
        // ZY1 = 0.25*(A@Y1) - 0.75*Y1 + 1.5*I
        gemm256<false><<<g * 4, 256, 0, stream>>>(s0, s1, s1, (void*)s2, 0.25f * INV_MSC, -0.75f, 1.5f * MSC, nullptr, b0);
        // Y2' = snorm*(Y1@ZY1)
        gemm256<false><<<g * 4, 256, 0, stream>>>(s1, s2, nullptr, (void*)s3, INV_MSC, 0.0f, 0.0f, snorm, b0);
        // Z2' = invs*(-0.5*(ZY1@A) + 1.5*ZY1)
        gemm256<false><<<g * 4, 256, 0, stream>>>(s2, s0, s2, (void*)s1, -0.5f * INV_MSC, 1.5f, 0.0f, invs, b0);
        // T = -0.5*(Z2'@Y2') + 1.5*I
        gemm256<false><<<g * 4, 256, 0, stream>>>(s1, s3, nullptr, (void*)s0, -0.5f * INV_MSC, 0.0f, 1.5f * MSC, nullptr, b0);
        // out = triu(Y2'@T) / MSC^2
        gemm256<true><<<g * 4, 256, 0, stream>>>(s3, s0, nullptr, d_out, 0.0f, 0.0f, 0.0f, nullptr, b0);
    }
}

// Round 8
// 424.968 us; speedup vs baseline: 1.0626x; 1.0626x over previous
//
#include <hip/hip_runtime.h>
#include <math.h>

// Problem constants
#define BB 256          // batch
#define CC 256          // channels
#define MN 196          // H*W
#define TRI 32896       // C*(C+1)/2

// Split-f16 storage: u32 = {lo16: f16(hi), hi16: f16(32v - hi)} at x32 scale.
#define MSC 32.0f
#define INV_MSC  (1.0f/32.0f)
#define INV_MSC2 (1.0f/1024.0f)

typedef _Float16 f16;
typedef f16   f16x8 __attribute__((ext_vector_type(8)));
typedef float f32x4 __attribute__((ext_vector_type(4)));
typedef unsigned u32x4 __attribute__((ext_vector_type(4)));

__device__ __forceinline__ unsigned pack_split(float v) {
    f16 h = (f16)v;
    f16 l = (f16)(v - (float)h);
    return (unsigned)__builtin_bit_cast(unsigned short, h) |
           ((unsigned)__builtin_bit_cast(unsigned short, l) << 16);
}
__device__ __forceinline__ float unpack_split(unsigned w) {
    f16 h = __builtin_bit_cast(f16, (unsigned short)(w & 0xffffu));
    f16 l = __builtin_bit_cast(f16, (unsigned short)(w >> 16));
    return (float)h + (float)l;
}
__device__ __forceinline__ f16x8 swap_pairs(f16x8 v) {
    return __builtin_shufflevector(v, v, 1, 0, 3, 2, 5, 4, 7, 6);
}
__device__ __forceinline__ void gload_lds16(const unsigned* g, const void* l) {
    __builtin_amdgcn_global_load_lds(
        (__attribute__((address_space(1))) void*)(size_t)g,
        (__attribute__((address_space(3))) void*)(unsigned)(size_t)l,
        16, 0, 0);
}

// ---------------------------------------------------------------------------
// Fused xsplit: per (b,c) row compute mean+var in-wave, write split-f16
// centered row padded K 196 -> 256 with zeros (so cov is a plain 256-K GEMM).
// xs[batch] is exactly 256x256 u32 = one slot.
// ---------------------------------------------------------------------------
__global__ __launch_bounds__(256) void xsplit_kernel(const float* __restrict__ x,
                                                     float* __restrict__ vr,
                                                     unsigned* __restrict__ xs, int b0) {
    int wave = (blockIdx.x * 256 + threadIdx.x) >> 6;   // bl*256 + c
    int lane = threadIdx.x & 63;
    int bl = wave >> 8;
    int c  = wave & 255;
    int bg = b0 + bl;
    const float* row = x + ((size_t)bg * CC + c) * MN;
    float a0 = row[lane], a1 = row[lane + 64], a2 = row[lane + 128];
    float a3 = (lane < MN - 192) ? row[lane + 192] : 0.0f;
    float s = a0 + a1 + a2 + a3;
    float q = a0 * a0 + a1 * a1 + a2 * a2 + a3 * a3;
    #pragma unroll
    for (int off = 32; off > 0; off >>= 1) {
        s += __shfl_xor(s, off, 64);
        q += __shfl_xor(q, off, 64);
    }
    float m = s * (1.0f / MN);
    if (lane == 0) vr[bg * CC + c] = q * (1.0f / MN) - m * m;
    unsigned* orow = xs + ((size_t)bl * CC + c) * 256;
    orow[lane]       = pack_split(MSC * (a0 - m));
    orow[lane + 64]  = pack_split(MSC * (a1 - m));
    orow[lane + 128] = pack_split(MSC * (a2 - m));
    orow[lane + 192] = (lane < 4) ? pack_split(MSC * (a3 - m)) : 0u;
}

// normA[b] = sum_c vr[b,c] (per chunk)
__global__ __launch_bounds__(256) void norm_kernel(const float* __restrict__ vr,
                                                   float* __restrict__ inv,
                                                   float* __restrict__ snorm,
                                                   float* __restrict__ invs, int b0) {
    __shared__ float red[256];
    int b = b0 + blockIdx.x, i = threadIdx.x;
    red[i] = vr[b * CC + i];
    __syncthreads();
    for (int s = 128; s > 0; s >>= 1) {
        if (i < s) red[i] += red[i + s];
        __syncthreads();
    }
    if (i == 0) {
        float n = red[0];
        inv[b] = 1.0f / n;
        float sq = sqrtf(n);
        snorm[b] = sq;
        invs[b] = 1.0f / sq;
    }
}

// ---------------------------------------------------------------------------
// Split-f16 MFMA GEMM, grid-parallelism-optimized.
// 64x64 tile, 256 threads = 4 waves (2x2), wave tile 32x32 (2x2 16x16 frags),
// mfma_f32_16x16x32_f16 x2 passes (bv / swap(bv)).
// 16 tiles/batch -> grid = g*16 = 1024 blocks = 4 blocks/CU: four
// UNSYNCHRONIZED blocks per CU interleave so each block's per-chunk barrier
// drain is hidden by the other three (TLP latency hiding). The 4x panel
// re-read is absorbed by L2: the XCD-chunked swizzle maps each batch's 16
// consecutive tiles to one XCD (~1MB working set vs 4MiB L2).
// K-chunk = 32 u32 (128B/row, 8 chunks); staging via global_load_lds w=16,
// both-sides XOR granule swizzle (granule ^= row&7) -> conflict-free b128.
// LDS = 2 bufs x (A 8KB + B 8KB) = 32 KiB.
// Epilogue: E/C bounced through a 16KB LDS tile (1KB/wave-inst coalesced).
// FINAL: triu(acc)*INV_MSC2 -> f32 out; ti>tj blocks exit early.
// ---------------------------------------------------------------------------
template <bool FINAL>
__global__ __launch_bounds__(256) void gemm256(const unsigned* __restrict__ Ag,
                                               const unsigned* __restrict__ Bg,
                                               const unsigned* __restrict__ Eg,
                                               void* __restrict__ Cg,
                                               const float alpha0, const float beta0,
                                               const float diag_add,
                                               const float* __restrict__ Sg, int b0) {
    __shared__ __align__(16) unsigned char smem[32768];
    // staging: A [2][64 rows][128B] at 0..16384 ; B at 16384..32768
    // epilogue union: tile[64][64] u32 (16KB)

    int bid = blockIdx.x;
    const int nwg = gridDim.x;
    if ((nwg & 7) == 0) {                   // bijective XCD-chunked swizzle
        const int cpx = nwg >> 3;
        bid = (bid & 7) * cpx + (bid >> 3);
    }
    const int bl = bid >> 4;
    const int t  = bid & 15;
    const int ti = t >> 2, tj = t & 3;      // 0..3 each
    if (FINAL && ti > tj) return;           // strictly-lower tiles unused
    const int bg = b0 + bl;
    const int tid  = threadIdx.x;
    const int lane = tid & 63;
    const int wid  = tid >> 6;              // 0..3
    const int wr = wid >> 1, wc = wid & 1;
    const int h = lane >> 4;                // 0..3 (k-group of MFMA A/B frag)
    const int d = lane & 15;                // frag row-within-16 / C col

    const unsigned* Abase = Ag + (size_t)bl * (CC * CC) + (size_t)(ti * 64) * 256;
    const unsigned* Bbase = Bg + (size_t)bl * (CC * CC) + (size_t)(tj * 64) * 256;

    // staging roles: waves 0-1 -> A rows (wid&1)*32..+31, waves 2-3 -> B.
    // lane -> (row-within-inst sr = lane>>3, dest granule p = lane&7);
    // source logical granule = p ^ (row&7) = p ^ sr.
    const unsigned* gpan = (wid < 2) ? Abase : Bbase;
    const int lbank = (wid < 2) ? 0 : 16384;
    const int rbase = (wid & 1) * 32;
    const int sr = lane >> 3;                           // 0..7
    const int sg = (lane & 7) ^ sr;                     // pre-swizzled src granule
    const unsigned* gsl = gpan + (size_t)(rbase + sr) * 256 + (sg << 2);

    auto STAGE = [&](int nb, int ks) {
        #pragma unroll
        for (int i = 0; i < 4; ++i)
            gload_lds16(gsl + (size_t)(i * 8) * 256 + ks * 32,
                        smem + lbank + nb * 8192 + (rbase + i * 8) * 128);
    };

    f32x4 acc[2][2];
    #pragma unroll
    for (int i = 0; i < 2; ++i)
        #pragma unroll
        for (int j = 0; j < 2; ++j) acc[i][j] = 0.0f;

    STAGE(0, 0);
    __syncthreads();
    #pragma unroll 1
    for (int ks = 0; ks < 8; ++ks) {
        const int nb = ks & 1;
        if (ks < 7) STAGE(nb ^ 1, ks + 1);
        const char* base = (const char*)smem + nb * 8192;
        #pragma unroll
        for (int kk = 0; kk < 2; ++kk) {
            // rows: wr*32+ib*16+d -> row&7 = d&7; granule (kk*4+h)^(d&7)
            const int swz = ((kk * 4 + h) ^ (d & 7)) << 4;
            f16x8 av[2], bv[2], bw[2];
            #pragma unroll
            for (int ib = 0; ib < 2; ++ib)
                av[ib] = *(const f16x8*)(base + (wr * 32 + ib * 16 + d) * 128 + swz);
            #pragma unroll
            for (int jb = 0; jb < 2; ++jb) {
                bv[jb] = *(const f16x8*)(base + 16384 + (wc * 32 + jb * 16 + d) * 128 + swz);
                bw[jb] = swap_pairs(bv[jb]);
            }
            #pragma unroll
            for (int ib = 0; ib < 2; ++ib)
                #pragma unroll
                for (int jb = 0; jb < 2; ++jb) {
                    acc[ib][jb] = __builtin_amdgcn_mfma_f32_16x16x32_f16(av[ib], bv[jb], acc[ib][jb], 0, 0, 0);
                    acc[ib][jb] = __builtin_amdgcn_mfma_f32_16x16x32_f16(av[ib], bw[jb], acc[ib][jb], 0, 0, 0);
                }
        }
        __syncthreads();   // staged chunk landed (vmcnt drained) + reads done
    }

    // C/D frag: col = lane&15 (=d), row = h*4 + q  (harness-verified)
    const int li0 = wr * 32 + h * 4;        // local row base (+ib*16+q)
    const int lj0 = wc * 32 + d;            // local col (+jb*16)
    const int gi0 = ti * 64 + li0;
    const int gj0 = tj * 64 + lj0;
    unsigned* tile = (unsigned*)smem;       // 64x64 u32 epilogue buffer

    if (!FINAL) {
        const float sc = (Sg != nullptr) ? Sg[bg] : 1.0f;
        const float al = alpha0 * sc;
        const float be = beta0 * sc;
        unsigned* Cb = (unsigned*)Cg + (size_t)bl * CC * CC;
        const unsigned* Eb = (Eg != nullptr) ? Eg + (size_t)bl * CC * CC : nullptr;

        if (Eb) {   // coalesced 1KB/wave-inst load of E tile into LDS
            #pragma unroll
            for (int it = 0; it < 4; ++it) {
                int f = it * 256 + tid;
                int r = f >> 4, c4 = f & 15;
                *(u32x4*)&tile[r * 64 + c4 * 4] =
                    *(const u32x4*)&Eb[(size_t)(ti * 64 + r) * CC + tj * 64 + c4 * 4];
            }
        }
        __syncthreads();
        // owners RMW their cells (cells partition the 64x64 tile exactly)
        #pragma unroll
        for (int ib = 0; ib < 2; ++ib)
            #pragma unroll
            for (int jb = 0; jb < 2; ++jb)
                #pragma unroll
                for (int q = 0; q < 4; ++q) {
                    int lr = li0 + ib * 16 + q;
                    int lc = lj0 + jb * 16;
                    float val = al * acc[ib][jb][q];
                    if (Eb) val += be * unpack_split(tile[lr * 64 + lc]);
                    if (gi0 + ib * 16 + q == gj0 + jb * 16) val += diag_add;
                    tile[lr * 64 + lc] = pack_split(val);
                }
        __syncthreads();
        #pragma unroll
        for (int it = 0; it < 4; ++it) {   // coalesced 1KB/wave-inst store
            int f = it * 256 + tid;
            int r = f >> 4, c4 = f & 15;
            *(u32x4*)&Cb[(size_t)(ti * 64 + r) * CC + tj * 64 + c4 * 4] =
                *(const u32x4*)&tile[r * 64 + c4 * 4];
        }
    } else {
        float* ob = (float*)Cg + (size_t)bg * TRI;
        #pragma unroll
        for (int ib = 0; ib < 2; ++ib)
            #pragma unroll
            for (int jb = 0; jb < 2; ++jb) {
                int gib = gi0 + ib * 16;
                int gj  = gj0 + jb * 16;
                #pragma unroll
                for (int q = 0; q < 4; ++q) {
                    int gi = gib + q;
                    if (gj >= gi)
                        ob[gi * CC - (gi * (gi - 1)) / 2 - gi + gj] = acc[ib][jb][q] * INV_MSC2;
                }
            }
    }
}

// ---------------------------------------------------------------------------
// Per chunk of g batches (4 slots of 256KB/batch):
//   xs  = split(MSC*(x-mu)), K padded to 256   -> s1
//   A   = Gram(xs)*inv/(MSC*MN)                -> s0   (plain gemm, Sg=inv)
//   Y1  = -0.5 A@A + 1.5 A                     -> s1
//   ZY1 = 0.25 A@Y1 - 0.75 Y1 + 1.5 I          -> s2
//   Y2' = sqrt(n)*(Y1@ZY1)                     -> s3
//   Z2' = (1/sqrt(n))*(-0.5 ZY1@A + 1.5 ZY1)   -> s1
//   T   = -0.5 Z2'@Y2' + 1.5 I                 -> s0
//   out = triu(Y2'@T)/MSC^2                    -> d_out
// Scalar scratch in the tail of d_out (only the last FINAL writes there).
// ---------------------------------------------------------------------------
extern "C" void kernel_launch(void* const* d_in, const int* in_sizes, int n_in,
                              void* d_out, int out_size, void* d_ws, size_t ws_size,
                              hipStream_t stream) {
    const float* x = (const float*)d_in[0];
    float* out = (float*)d_out;
    unsigned* ws = (unsigned*)d_ws;

    const int SCR = BB * CC + 3 * BB;           // vr, inv, snorm, invs
    float* vr    = out + (out_size - SCR);
    float* inv   = vr + BB * CC;
    float* snorm = inv + BB;
    float* invs  = snorm + BB;

    size_t per_b = 4ull * CC * CC * sizeof(unsigned);   // 1 MiB per batch
    int gmax = (int)(ws_size / per_b);
    int g = 1;
    while (g * 2 <= gmax && g * 2 <= BB) g *= 2;

    size_t slotf = (size_t)g * CC * CC;
    unsigned* s0 = ws;
    unsigned* s1 = ws + slotf;
    unsigned* s2 = ws + 2 * slotf;
    unsigned* s3 = ws + 3 * slotf;

    for (int b0 = 0; b0 < BB; b0 += g) {
        xsplit_kernel<<<g * 64, 256, 0, stream>>>(x, vr, s1, b0);
        norm_kernel<<<g, 256, 0, stream>>>(vr, inv, snorm, invs, b0);
        // A = Gram(xs) * inv / (MSC*MN)   (stored MSC-scaled)
        gemm256<false><<<g * 16, 256, 0, stream>>>(s1, s1, nullptr, (void*)s0,
                                                   1.0f / (MSC * MN), 0.0f, 0.0f, inv, b0);
        // Y1 = -0.5*(A@A) + 1.5*A
        gemm256<false><<<g * 16, 256, 0, stream>>>(s0, s0, s0, (void*)s1, -0.5f * INV_MSC, 1.5f, 0.0f, nullptr, b0);
        // ZY1 = 0.25*(A@Y1) - 0.75*Y1 + 1.5*I
        gemm256<false><<<g * 16, 256, 0, stream>>>(s0, s1, s1, (void*)s2, 0.25f * INV_MSC, -0.75f, 1.5f * MSC, nullptr, b0);
        // Y2' = snorm*(Y1@ZY1)
        gemm256<false><<<g * 16, 256, 0, stream>>>(s1, s2, nullptr, (void*)s3, INV_MSC, 0.0f, 0.0f, snorm, b0);
        // Z2' = invs*(-0.5*(ZY1@A) + 1.5*ZY1)
        gemm256<false><<<g * 16, 256, 0, stream>>>(s2, s0, s2, (void*)s1, -0.5f * INV_MSC, 1.5f, 0.0f, invs, b0);
        // T = -0.5*(Z2'@Y2') + 1.5*I
        gemm256<false><<<g * 16, 256, 0, stream>>>(s1, s3, nullptr, (void*)s0, -0.5f * INV_MSC, 0.0f, 1.5f * MSC, nullptr, b0);
        // out = triu(Y2'@T) / MSC^2
        gemm256<true><<<g * 16, 256, 0, stream>>>(s3, s0, nullptr, d_out, 0.0f, 0.0f, 0.0f, nullptr, b0);
    }
}

// Round 9
// 400.283 us; speedup vs baseline: 1.1281x; 1.0617x over previous
//
#include <hip/hip_runtime.h>
#include <math.h>

// Problem constants
#define BB 256          // batch
#define CC 256          // channels
#define MN 196          // H*W
#define TRI 32896       // C*(C+1)/2

// Split-f16 storage: u32 = {lo16: f16(hi), hi16: f16(32v - hi)} at x32 scale.
#define MSC 32.0f
#define INV_MSC  (1.0f/32.0f)
#define INV_MSC2 (1.0f/1024.0f)

typedef _Float16 f16;
typedef f16   f16x8 __attribute__((ext_vector_type(8)));
typedef float f32x4 __attribute__((ext_vector_type(4)));
typedef unsigned u32x4 __attribute__((ext_vector_type(4)));

#define WAITVM4  asm volatile("s_waitcnt vmcnt(4)" ::: "memory")
#define WAITVM0  asm volatile("s_waitcnt vmcnt(0)" ::: "memory")
#define WAITLGKM asm volatile("s_waitcnt lgkmcnt(0)" ::: "memory")
#define SCHEDB   __builtin_amdgcn_sched_barrier(0)
#define BARRIER  __builtin_amdgcn_s_barrier()

__device__ __forceinline__ unsigned pack_split(float v) {
    f16 h = (f16)v;
    f16 l = (f16)(v - (float)h);
    return (unsigned)__builtin_bit_cast(unsigned short, h) |
           ((unsigned)__builtin_bit_cast(unsigned short, l) << 16);
}
__device__ __forceinline__ float unpack_split(unsigned w) {
    f16 h = __builtin_bit_cast(f16, (unsigned short)(w & 0xffffu));
    f16 l = __builtin_bit_cast(f16, (unsigned short)(w >> 16));
    return (float)h + (float)l;
}
__device__ __forceinline__ f16x8 swap_pairs(f16x8 v) {
    return __builtin_shufflevector(v, v, 1, 0, 3, 2, 5, 4, 7, 6);
}
__device__ __forceinline__ void gload_lds16(const unsigned* g, const void* l) {
    __builtin_amdgcn_global_load_lds(
        (__attribute__((address_space(1))) void*)(size_t)g,
        (__attribute__((address_space(3))) void*)(unsigned)(size_t)l,
        16, 0, 0);
}

// ---------------------------------------------------------------------------
// Fused xsplit: per (b,c) row compute mean+var in-wave, write split-f16
// centered row padded K 196 -> 256 with zeros. xs[batch] = 256x256 u32.
// ---------------------------------------------------------------------------
__global__ __launch_bounds__(256) void xsplit_kernel(const float* __restrict__ x,
                                                     float* __restrict__ vr,
                                                     unsigned* __restrict__ xs, int b0) {
    int wave = (blockIdx.x * 256 + threadIdx.x) >> 6;   // bl*256 + c
    int lane = threadIdx.x & 63;
    int bl = wave >> 8;
    int c  = wave & 255;
    int bg = b0 + bl;
    const float* row = x + ((size_t)bg * CC + c) * MN;
    float a0 = row[lane], a1 = row[lane + 64], a2 = row[lane + 128];
    float a3 = (lane < MN - 192) ? row[lane + 192] : 0.0f;
    float s = a0 + a1 + a2 + a3;
    float q = a0 * a0 + a1 * a1 + a2 * a2 + a3 * a3;
    #pragma unroll
    for (int off = 32; off > 0; off >>= 1) {
        s += __shfl_xor(s, off, 64);
        q += __shfl_xor(q, off, 64);
    }
    float m = s * (1.0f / MN);
    if (lane == 0) vr[bg * CC + c] = q * (1.0f / MN) - m * m;
    unsigned* orow = xs + ((size_t)bl * CC + c) * 256;
    orow[lane]       = pack_split(MSC * (a0 - m));
    orow[lane + 64]  = pack_split(MSC * (a1 - m));
    orow[lane + 128] = pack_split(MSC * (a2 - m));
    orow[lane + 192] = (lane < 4) ? pack_split(MSC * (a3 - m)) : 0u;
}

// normA[b] = sum_c vr[b,c] (per chunk)
__global__ __launch_bounds__(256) void norm_kernel(const float* __restrict__ vr,
                                                   float* __restrict__ inv,
                                                   float* __restrict__ snorm,
                                                   float* __restrict__ invs, int b0) {
    __shared__ float red[256];
    int b = b0 + blockIdx.x, i = threadIdx.x;
    red[i] = vr[b * CC + i];
    __syncthreads();
    for (int s = 128; s > 0; s >>= 1) {
        if (i < s) red[i] += red[i + s];
        __syncthreads();
    }
    if (i == 0) {
        float n = red[0];
        inv[b] = 1.0f / n;
        float sq = sqrtf(n);
        snorm[b] = sq;
        invs[b] = 1.0f / sq;
    }
}

// ---------------------------------------------------------------------------
// Split-f16 MFMA GEMM with counted-vmcnt 3-buffer pipeline (T4/m218 pattern).
// 64x64 tile, 256 thr = 4 waves (2x2), wave 32x32 (2x2 16x16 frags), x2
// passes (bv / swap(bv)). Grid = g*16 (16 tiles/batch).
// K-chunk = 32 u32; LDS = 3 bufs x (A 8KB + B 8KB) = 48 KiB -> 3 blocks/CU.
// Per chunk (fully unrolled, ks=0..7):
//   ds_read 8x b128 -> regs; lgkmcnt(0); sched_barrier
//   STAGE(chunk ks+2) -> buf[(ks+2)%3]   (released at barrier ks-1)
//   16 MFMA; sched_barrier; vmcnt(4) [never 0 in-loop]; s_barrier
// Each wave's vmcnt(4) proves ITS chunk-(ks+1) loads landed; the barrier
// makes it collective (m218). Loads stay 2 chunks deep across barriers.
// Both-sides XOR granule swizzle (granule ^= row&7) as verified in R8.
// Epilogue: E/C bounced through a 16KB LDS tile (coalesced 1KB/wave-inst).
// FINAL: triu(acc)*INV_MSC2 -> f32 out; ti>tj blocks exit early.
// ---------------------------------------------------------------------------
template <bool FINAL>
__global__ __launch_bounds__(256) void gemm256(const unsigned* __restrict__ Ag,
                                               const unsigned* __restrict__ Bg,
                                               const unsigned* __restrict__ Eg,
                                               void* __restrict__ Cg,
                                               const float alpha0, const float beta0,
                                               const float diag_add,
                                               const float* __restrict__ Sg, int b0) {
    __shared__ __align__(16) unsigned char smem[49152];
    // buf b: A-half [b*16384, +8192), B-half [b*16384+8192, +8192)
    // epilogue union: tile[64][64] u32 (16KB at offset 0)

    int bid = blockIdx.x;
    const int nwg = gridDim.x;
    if ((nwg & 7) == 0) {                   // bijective XCD-chunked swizzle
        const int cpx = nwg >> 3;
        bid = (bid & 7) * cpx + (bid >> 3);
    }
    const int bl = bid >> 4;
    const int t  = bid & 15;
    const int ti = t >> 2, tj = t & 3;      // 0..3 each
    if (FINAL && ti > tj) return;           // strictly-lower tiles unused
    const int bg = b0 + bl;
    const int tid  = threadIdx.x;
    const int lane = tid & 63;
    const int wid  = tid >> 6;              // 0..3
    const int wr = wid >> 1, wc = wid & 1;
    const int h = lane >> 4;                // 0..3 (k-group of MFMA A/B frag)
    const int d = lane & 15;                // frag row-within-16 / C col

    const unsigned* Abase = Ag + (size_t)bl * (CC * CC) + (size_t)(ti * 64) * 256;
    const unsigned* Bbase = Bg + (size_t)bl * (CC * CC) + (size_t)(tj * 64) * 256;

    // staging: waves 0-1 -> A rows (wid&1)*32..+31, waves 2-3 -> B.
    // source logical granule = (lane&7) ^ (row&7): both-sides involution.
    const unsigned* gpan = (wid < 2) ? Abase : Bbase;
    const int lbank = (wid < 2) ? 0 : 8192;
    const int rbase = (wid & 1) * 32;
    const int sr = lane >> 3;                           // 0..7
    const int sg = (lane & 7) ^ sr;                     // pre-swizzled src granule
    const unsigned* gsl = gpan + (size_t)(rbase + sr) * 256 + (sg << 2);

    auto STAGE = [&](int buf, int ks) {
        #pragma unroll
        for (int i = 0; i < 4; ++i)
            gload_lds16(gsl + (size_t)(i * 8) * 256 + ks * 32,
                        smem + buf * 16384 + lbank + (rbase + i * 8) * 128);
    };

    f32x4 acc[2][2];
    #pragma unroll
    for (int i = 0; i < 2; ++i)
        #pragma unroll
        for (int j = 0; j < 2; ++j) acc[i][j] = 0.0f;

    // prologue: chunks 0,1 in flight; wait own chunk-0 (vmcnt 8->4); collective
    STAGE(0, 0);
    STAGE(1, 1);
    WAITVM4;
    BARRIER;
    SCHEDB;

    #pragma unroll
    for (int ks = 0; ks < 8; ++ks) {
        const int buf = ks % 3;
        const char* base = (const char*)smem + buf * 16384;
        f16x8 av[2][2], bv[2][2];
        #pragma unroll
        for (int kk = 0; kk < 2; ++kk) {
            const int swz = ((kk * 4 + h) ^ (d & 7)) << 4;
            #pragma unroll
            for (int ib = 0; ib < 2; ++ib)
                av[kk][ib] = *(const f16x8*)(base + (wr * 32 + ib * 16 + d) * 128 + swz);
            #pragma unroll
            for (int jb = 0; jb < 2; ++jb)
                bv[kk][jb] = *(const f16x8*)(base + 8192 + (wc * 32 + jb * 16 + d) * 128 + swz);
        }
        WAITLGKM;           // own ds_reads of buf done (regs valid)
        SCHEDB;             // rule 18: nothing crosses (incl. the reads above)
        if (ks + 2 < 8) STAGE((ks + 2) % 3, ks + 2);   // buf released at bar ks-1
        #pragma unroll
        for (int kk = 0; kk < 2; ++kk) {
            f16x8 bw0 = swap_pairs(bv[kk][0]);
            f16x8 bw1 = swap_pairs(bv[kk][1]);
            #pragma unroll
            for (int ib = 0; ib < 2; ++ib) {
                acc[ib][0] = __builtin_amdgcn_mfma_f32_16x16x32_f16(av[kk][ib], bv[kk][0], acc[ib][0], 0, 0, 0);
                acc[ib][0] = __builtin_amdgcn_mfma_f32_16x16x32_f16(av[kk][ib], bw0,       acc[ib][0], 0, 0, 0);
                acc[ib][1] = __builtin_amdgcn_mfma_f32_16x16x32_f16(av[kk][ib], bv[kk][1], acc[ib][1], 0, 0, 0);
                acc[ib][1] = __builtin_amdgcn_mfma_f32_16x16x32_f16(av[kk][ib], bw1,       acc[ib][1], 0, 0, 0);
            }
        }
        SCHEDB;             // keep MFMA above the wait (overlap)
        if (ks < 6) { WAITVM4; } else { WAITVM0; }   // own chunk ks+1 landed
        BARRIER;            // collective: buf[(ks+1)%3] published, buf[ks%3] free
        SCHEDB;
    }

    // C/D frag: col = lane&15 (=d), row = h*4 + q  (harness-verified)
    const int li0 = wr * 32 + h * 4;        // local row base (+ib*16+q)
    const int lj0 = wc * 32 + d;            // local col (+jb*16)
    const int gi0 = ti * 64 + li0;
    const int gj0 = tj * 64 + lj0;
    unsigned* tile = (unsigned*)smem;       // 64x64 u32 epilogue buffer

    if (!FINAL) {
        const float sc = (Sg != nullptr) ? Sg[bg] : 1.0f;
        const float al = alpha0 * sc;
        const float be = beta0 * sc;
        unsigned* Cb = (unsigned*)Cg + (size_t)bl * CC * CC;
        const unsigned* Eb = (Eg != nullptr) ? Eg + (size_t)bl * CC * CC : nullptr;

        if (Eb) {   // coalesced 1KB/wave-inst load of E tile into LDS
            #pragma unroll
            for (int it = 0; it < 4; ++it) {
                int f = it * 256 + tid;
                int r = f >> 4, c4 = f & 15;
                *(u32x4*)&tile[r * 64 + c4 * 4] =
                    *(const u32x4*)&Eb[(size_t)(ti * 64 + r) * CC + tj * 64 + c4 * 4];
            }
        }
        __syncthreads();
        // owners RMW their cells (cells partition the 64x64 tile exactly)
        #pragma unroll
        for (int ib = 0; ib < 2; ++ib)
            #pragma unroll
            for (int jb = 0; jb < 2; ++jb)
                #pragma unroll
                for (int q = 0; q < 4; ++q) {
                    int lr = li0 + ib * 16 + q;
                    int lc = lj0 + jb * 16;
                    float val = al * acc[ib][jb][q];
                    if (Eb) val += be * unpack_split(tile[lr * 64 + lc]);
                    if (gi0 + ib * 16 + q == gj0 + jb * 16) val += diag_add;
                    tile[lr * 64 + lc] = pack_split(val);
                }
        __syncthreads();
        #pragma unroll
        for (int it = 0; it < 4; ++it) {   // coalesced 1KB/wave-inst store
            int f = it * 256 + tid;
            int r = f >> 4, c4 = f & 15;
            *(u32x4*)&Cb[(size_t)(ti * 64 + r) * CC + tj * 64 + c4 * 4] =
                *(const u32x4*)&tile[r * 64 + c4 * 4];
        }
    } else {
        float* ob = (float*)Cg + (size_t)bg * TRI;
        #pragma unroll
        for (int ib = 0; ib < 2; ++ib)
            #pragma unroll
            for (int jb = 0; jb < 2; ++jb) {
                int gib = gi0 + ib * 16;
                int gj  = gj0 + jb * 16;
                #pragma unroll
                for (int q = 0; q < 4; ++q) {
                    int gi = gib + q;
                    if (gj >= gi)
                        ob[gi * CC - (gi * (gi - 1)) / 2 - gi + gj] = acc[ib][jb][q] * INV_MSC2;
                }
            }
    }
}

// ---------------------------------------------------------------------------
// Per chunk of g batches (4 slots of 256KB/batch):
//   xs  = split(MSC*(x-mu)), K padded to 256   -> s1
//   A   = Gram(xs)*inv/(MSC*MN)                -> s0
//   Y1  = -0.5 A@A + 1.5 A                     -> s1
//   ZY1 = 0.25 A@Y1 - 0.75 Y1 + 1.5 I          -> s2
//   Y2' = sqrt(n)*(Y1@ZY1)                     -> s3
//   Z2' = (1/sqrt(n))*(-0.5 ZY1@A + 1.5 ZY1)   -> s1
//   T   = -0.5 Z2'@Y2' + 1.5 I                 -> s0
//   out = triu(Y2'@T)/MSC^2                    -> d_out
// Scalar scratch in the tail of d_out (only the last FINAL writes there).
// ---------------------------------------------------------------------------
extern "C" void kernel_launch(void* const* d_in, const int* in_sizes, int n_in,
                              void* d_out, int out_size, void* d_ws, size_t ws_size,
                              hipStream_t stream) {
    const float* x = (const float*)d_in[0];
    float* out = (float*)d_out;
    unsigned* ws = (unsigned*)d_ws;

    const int SCR = BB * CC + 3 * BB;           // vr, inv, snorm, invs
    float* vr    = out + (out_size - SCR);
    float* inv   = vr + BB * CC;
    float* snorm = inv + BB;
    float* invs  = snorm + BB;

    size_t per_b = 4ull * CC * CC * sizeof(unsigned);   // 1 MiB per batch
    int gmax = (int)(ws_size / per_b);
    int g = 1;
    while (g * 2 <= gmax && g * 2 <= BB) g *= 2;

    size_t slotf = (size_t)g * CC * CC;
    unsigned* s0 = ws;
    unsigned* s1 = ws + slotf;
    unsigned* s2 = ws + 2 * slotf;
    unsigned* s3 = ws + 3 * slotf;

    for (int b0 = 0; b0 < BB; b0 += g) {
        xsplit_kernel<<<g * 64, 256, 0, stream>>>(x, vr, s1, b0);
        norm_kernel<<<g, 256, 0, stream>>>(vr, inv, snorm, invs, b0);
        // A = Gram(xs) * inv / (MSC*MN)   (stored MSC-scaled)
        gemm256<false><<<g * 16, 256, 0, stream>>>(s1, s1, nullptr, (void*)s0,
                                                   1.0f / (MSC * MN), 0.0f, 0.0f, inv, b0);
        // Y1 = -0.5*(A@A) + 1.5*A
        gemm256<false><<<g * 16, 256, 0, stream>>>(s0, s0, s0, (void*)s1, -0.5f * INV_MSC, 1.5f, 0.0f, nullptr, b0);
        // ZY1 = 0.25*(A@Y1) - 0.75*Y1 + 1.5*I
        gemm256<false><<<g * 16, 256, 0, stream>>>(s0, s1, s1, (void*)s2, 0.25f * INV_MSC, -0.75f, 1.5f * MSC, nullptr, b0);
        // Y2' = snorm*(Y1@ZY1)
        gemm256<false><<<g * 16, 256, 0, stream>>>(s1, s2, nullptr, (void*)s3, INV_MSC, 0.0f, 0.0f, snorm, b0);
        // Z2' = invs*(-0.5*(ZY1@A) + 1.5*ZY1)
        gemm256<false><<<g * 16, 256, 0, stream>>>(s2, s0, s2, (void*)s1, -0.5f * INV_MSC, 1.5f, 0.0f, invs, b0);
        // T = -0.5*(Z2'@Y2') + 1.5*I
        gemm256<false><<<g * 16, 256, 0, stream>>>(s1, s3, nullptr, (void*)s0, -0.5f * INV_MSC, 0.0f, 1.5f * MSC, nullptr, b0);
        // out = triu(Y2'@T) / MSC^2
        gemm256<true><<<g * 16, 256, 0, stream>>>(s3, s0, nullptr, d_out, 0.0f, 0.0f, 0.0f, nullptr, b0);
    }
}